// Round 11
// baseline (197.985 us; speedup 1.0000x reference)
//
#include <hip/hip_runtime.h>
#include <hip/hip_bf16.h>

using bf16 = __hip_bfloat16;
typedef __attribute__((ext_vector_type(8))) short s16x8;
typedef __attribute__((ext_vector_type(4))) float f32x4;
typedef unsigned int u32;

__device__ __forceinline__ float b2f(short u) {
    union { float f; u32 i; } x; x.i = ((u32)(unsigned short)u) << 16; return x.f;
}
__device__ __forceinline__ short f2b(float f) {
    bf16 h = (bf16)f; return *(short*)&h;
}

// ---- register-pipelined GEMM core: C = A @ W^T + bias ----
// A/W each either fp32 (convert-on-stage from pristine d_in) or bf16 (ws).
// Global->VGPR staging for tile k+1 issued after the barrier, overlapping
// ds_read+MFMA of tile k. 256 threads = 4 waves (2x2).
template<int BM, int BN, bool A_F32, bool B_F32, bool OUT_F32>
__device__ __forceinline__ void gemm_pipe(
    const void* __restrict__ A, const void* __restrict__ W,
    const float* __restrict__ bias, void* __restrict__ out,
    int m0, int n0, int N, int K, bf16* lA, bf16* lB) {
    constexpr int WM = BM / 2, WN = BN / 2, FM = WM / 16, FN = WN / 16;
    constexpr int SA = BM / 64, SB = BN / 64;   // 16B reg slots per thread
    const int tid = threadIdx.x;
    const int wave = tid >> 6, lane = tid & 63;
    const int wr = wave >> 1, wc = wave & 1;
    const int quad = lane >> 4, lm = lane & 15;
    uint4 ra[SA], rb[SB];

    auto cvt8 = [](const float* g) -> uint4 {
        float4 f0 = *(const float4*)g;
        float4 f1 = *(const float4*)(g + 4);
        union { uint4 u; short h[8]; } p;
        p.h[0] = f2b(f0.x); p.h[1] = f2b(f0.y); p.h[2] = f2b(f0.z); p.h[3] = f2b(f0.w);
        p.h[4] = f2b(f1.x); p.h[5] = f2b(f1.y); p.h[6] = f2b(f1.z); p.h[7] = f2b(f1.w);
        return p.u;
    };
    auto loadA = [&](int k0) {
#pragma unroll
        for (int q = 0; q < SA; ++q) {
            const int sl = q * 256 + tid, row = sl >> 2, col = (sl & 3) * 8;
            if (A_F32) ra[q] = cvt8((const float*)A + (size_t)(m0 + row) * K + k0 + col);
            else       ra[q] = *(const uint4*)((const bf16*)A + (size_t)(m0 + row) * K + k0 + col);
        }
    };
    auto loadB = [&](int k0) {
#pragma unroll
        for (int q = 0; q < SB; ++q) {
            const int sl = q * 256 + tid, row = sl >> 2, col = (sl & 3) * 8;
            if (B_F32) rb[q] = cvt8((const float*)W + (size_t)(n0 + row) * K + k0 + col);
            else       rb[q] = *(const uint4*)((const bf16*)W + (size_t)(n0 + row) * K + k0 + col);
        }
    };

    f32x4 acc[FM][FN] = {};
    loadA(0); loadB(0);
    for (int k0 = 0; k0 < K; k0 += 32) {
#pragma unroll
        for (int q = 0; q < SA; ++q) *(uint4*)(lA + (q * 256 + tid) * 8) = ra[q];
#pragma unroll
        for (int q = 0; q < SB; ++q) *(uint4*)(lB + (q * 256 + tid) * 8) = rb[q];
        __syncthreads();
        if (k0 + 32 < K) { loadA(k0 + 32); loadB(k0 + 32); }   // overlaps MFMA below
        s16x8 af[FM], bf_[FN];
#pragma unroll
        for (int i = 0; i < FM; ++i)
            af[i] = *(const s16x8*)&lA[(wr * WM + i * 16 + lm) * 32 + quad * 8];
#pragma unroll
        for (int j = 0; j < FN; ++j)
            bf_[j] = *(const s16x8*)&lB[(wc * WN + j * 16 + lm) * 32 + quad * 8];
#pragma unroll
        for (int i = 0; i < FM; ++i)
#pragma unroll
            for (int j = 0; j < FN; ++j)
                acc[i][j] = __builtin_amdgcn_mfma_f32_16x16x32_bf16(af[i], bf_[j], acc[i][j], 0, 0, 0);
        __syncthreads();
    }
#pragma unroll
    for (int i = 0; i < FM; ++i) {
        const int rbase = m0 + wr * WM + i * 16 + quad * 4;
#pragma unroll
        for (int j = 0; j < FN; ++j) {
            const int col = n0 + wc * WN + j * 16 + lm;
            const float bv = bias[col];
#pragma unroll
            for (int r = 0; r < 4; ++r) {
                float v = acc[i][j][r] + bv;
                size_t off = (size_t)(rbase + r) * N + col;
                if (OUT_F32) ((float*)out)[off] = v;
                else         ((bf16*)out)[off] = (bf16)v;
            }
        }
    }
}

// ---- fused Q/K/V projection: 768 blocks (3/CU), 128x64 tiles, XCD-swizzled.
// All operands read pristine fp32 from d_in, converted in the staging path. ----
__global__ __launch_bounds__(256)
void proj_kernel(const float* __restrict__ q, const float* __restrict__ k,
                 const float* __restrict__ v,
                 const float* __restrict__ Qk, const float* __restrict__ Kk,
                 const float* __restrict__ Vk,
                 const float* __restrict__ Qb, const float* __restrict__ Kb,
                 const float* __restrict__ Vb,
                 float* __restrict__ qp, float* __restrict__ kp,
                 bf16* __restrict__ vp) {
    __shared__ __align__(16) bf16 lA[128 * 32];
    __shared__ __align__(16) bf16 lB[64 * 32];
    const int L = blockIdx.x, xcd = L & 7, i = L >> 3;
    const int m0 = (xcd * 2 + i / 48) * 128;
    const int nid = i % 48;
    if (nid < 10)
        gemm_pipe<128, 64, true, true, true >(q, Qk, Qb, qp, m0, nid * 64, 640, 640, lA, lB);
    else if (nid < 20)
        gemm_pipe<128, 64, true, true, true >(k, Kk, Kb, kp, m0, (nid - 10) * 64, 640, 640, lA, lB);
    else
        gemm_pipe<128, 64, true, true, false>(v, Vk, Vb, vp, m0, (nid - 20) * 64, 1792, 640, lA, lB);
}

// ---- collapse GEMM: 320 blocks of 64x64, K=1792, XCD-swizzled.
// A = atn (ws bf16); W = Ck pristine fp32 convert-on-stage. ----
__global__ __launch_bounds__(256)
void collapse_kernel(const bf16* __restrict__ atn, const float* __restrict__ Ck,
                     const float* __restrict__ Cb, float* __restrict__ out) {
    __shared__ __align__(16) bf16 lA[64 * 32];
    __shared__ __align__(16) bf16 lB[64 * 32];
    const int L = blockIdx.x, xcd = L & 7, i = L >> 3;
    const int m0 = (xcd * 4 + i / 10) * 64;
    const int n0 = (i % 10) * 64;
    gemm_pipe<64, 64, false, true, true>(atn, Ck, Cb, out, m0, n0, 640, 1792, lA, lB);
}

// ---- attention core (R9's attn_v4): one block per position, XCD-swizzled.
// Weight tensors Kb/Vb/Sk/Sb read directly as pristine fp32. ----
__global__ __launch_bounds__(256)
void attn_v4(const float* __restrict__ qp, const float* __restrict__ kp,
             const bf16* __restrict__ vp,
             const float* __restrict__ Kbf, const float* __restrict__ Vbf,
             const float* __restrict__ Skf, const float* __restrict__ Sbf,
             bf16* __restrict__ atn) {
    const int pos = ((blockIdx.x & 7) << 8) | (blockIdx.x >> 3);  // XCD-contiguous
    const int b = pos >> 10, l = pos & 1023;
    const int t = threadIdx.x;
    __shared__ float qs[640];
    __shared__ float sc5[5 * 32];
    __shared__ float sc14[14 * 32];
    __shared__ float w14T[32 * 14];   // transposed: [tap][head]

    if (t < 160) ((float4*)qs)[t] = ((const float4*)(qp + (size_t)pos * 640))[t];
    __syncthreads();

    // Phase A: score[s][j] = q[s].kwin[s][j]; 8 lanes/dot, stride-32 interleave
    {
        const int j = t >> 3, p = t & 7;
#pragma unroll
        for (int s = 0; s < 5; ++s) {
            const int dil = (s < 2) ? 1 : (1 << (s - 1));
            const int pl = (31 * dil) >> 1;
            const int row = l + j * dil - pl;
            const float* q = qs + s * 128 + p * 4;
            float acc = 0.f;
            if (row >= 0 && row < 1024) {
                const float* kr = kp + (size_t)((b << 10) | row) * 640 + s * 128 + p * 4;
#pragma unroll
                for (int g = 0; g < 4; ++g) {
                    float4 kv = *(const float4*)(kr + g * 32);
                    float4 qv = *(const float4*)(q + g * 32);
                    acc += qv.x * kv.x + qv.y * kv.y + qv.z * kv.z + qv.w * kv.w;
                }
            } else {
                const float* kb = Kbf + s * 128 + p * 4;   // pad rows project the bias
#pragma unroll
                for (int g = 0; g < 4; ++g) {
                    float4 kv = *(const float4*)(kb + g * 32);
                    float4 qv = *(const float4*)(q + g * 32);
                    acc += qv.x * kv.x + qv.y * kv.y + qv.z * kv.z + qv.w * kv.w;
                }
            }
            acc += __shfl_xor(acc, 1);
            acc += __shfl_xor(acc, 2);
            acc += __shfl_xor(acc, 4);
            if (p == 0) sc5[s * 32 + j] = acc;
        }
    }
    __syncthreads();

    // Phase B: supersample + positional resampling (448 outputs), fp32 Sk
    for (int idx = t; idx < 448; idx += 256) {
        const int h = idx >> 5;
        const int s = (h < 5) ? 0 : (h < 10) ? 1 : (h < 12) ? 2 : (h == 12) ? 3 : 4;
        const float* sk = Skf + idx * 32;
        const float* sc = sc5 + s * 32;
        float acc = Sbf[idx];
#pragma unroll
        for (int g = 0; g < 32; g += 4) {
            float4 kk = *(const float4*)(sk + g);
            acc += sc[g] * kk.x + sc[g + 1] * kk.y + sc[g + 2] * kk.z + sc[g + 3] * kk.w;
        }
        sc14[idx] = acc;
    }
    __syncthreads();

    // Phase C: softmax, 16 lanes/head (2 taps each), shuffle-reduce width 16
    if (t < 224) {
        const int h = t >> 4, u = t & 15;
        float s0 = sc14[h * 32 + u], s1 = sc14[h * 32 + u + 16];
        float mx = fmaxf(s0, s1);
#pragma unroll
        for (int m = 1; m < 16; m <<= 1) mx = fmaxf(mx, __shfl_xor(mx, m));
        float e0 = __expf(s0 - mx), e1 = __expf(s1 - mx);
        float sum = e0 + e1;
#pragma unroll
        for (int m = 1; m < 16; m <<= 1) sum += __shfl_xor(sum, m);
        float inv = 1.f / sum;
        w14T[u * 14 + h] = e0 * inv;
        w14T[(u + 16) * 14 + h] = e1 * inv;
    }
    __syncthreads();

    // Phase D: attn[h][d8] = sum_j w[j][h] * vwin[h][j][d8]
    if (t < 224) {
        const int h = t >> 4, d8 = (t & 15) * 8;
        const int dil = (h < 10) ? 1 : (h < 12) ? 2 : (h == 12) ? 4 : 8;
        const int pl = (31 * dil) >> 1;
        const int col = h * 128 + d8;
        float vb[8];
#pragma unroll
        for (int r = 0; r < 8; ++r) vb[r] = Vbf[col + r];  // pad-row V (bias proj)
        float acc[8] = {};
#pragma unroll
        for (int j = 0; j < 32; ++j) {
            const int row = l + j * dil - pl;
            const float w = w14T[j * 14 + h];
            if (row >= 0 && row < 1024) {
                s16x8 v8 = *(const s16x8*)((const short*)vp + (size_t)((b << 10) | row) * 1792 + col);
#pragma unroll
                for (int r = 0; r < 8; ++r) acc[r] += w * b2f(v8[r]);
            } else {
#pragma unroll
                for (int r = 0; r < 8; ++r) acc[r] += w * vb[r];
            }
        }
        union { uint4 u; short h16[8]; } o;
#pragma unroll
        for (int r = 0; r < 8; ++r) o.h16[r] = f2b(acc[r]);
        *(uint4*)((short*)atn + (size_t)pos * 1792 + col) = o.u;
    }
}

extern "C" void kernel_launch(void* const* d_in, const int* in_sizes, int n_in,
                              void* d_out, int out_size, void* d_ws, size_t ws_size,
                              hipStream_t stream) {
    const int M = 2048;
    char* w = (char*)d_ws;
    size_t off = 0;
    auto alloc = [&](size_t bytes) -> char* {
        off = (off + 255) & ~(size_t)255;
        char* p = w + off; off += bytes; return p;
    };
    float* qp = (float*)alloc((size_t)M * 640 * 4);
    float* kp = (float*)alloc((size_t)M * 640 * 4);
    bf16*  vp = (bf16*)alloc((size_t)M * 1792 * 2);
    bf16*  atn = (bf16*)alloc((size_t)M * 1792 * 2);

    const float* query = (const float*)d_in[0];
    const float* key   = (const float*)d_in[1];
    const float* value = (const float*)d_in[2];
    const float* Qk = (const float*)d_in[3];
    const float* Qb = (const float*)d_in[4];
    const float* Kk = (const float*)d_in[5];
    const float* Kb = (const float*)d_in[6];
    const float* Vk = (const float*)d_in[7];
    const float* Vb = (const float*)d_in[8];
    const float* Sk = (const float*)d_in[9];
    const float* Sb = (const float*)d_in[10];
    const float* Ck = (const float*)d_in[11];
    const float* Cb = (const float*)d_in[12];

    dim3 blk(256);
    proj_kernel<<<dim3(768), blk, 0, stream>>>(query, key, value,
                                               Qk, Kk, Vk, Qb, Kb, Vb, qp, kp, vp);
    attn_v4<<<dim3(2048), blk, 0, stream>>>(qp, kp, vp, Kb, Vb, Sk, Sb, atn);
    collapse_kernel<<<dim3(320), blk, 0, stream>>>(atn, Ck, Cb, (float*)d_out);
}

// Round 12
// 165.586 us; speedup vs baseline: 1.1957x; 1.1957x over previous
//
#include <hip/hip_runtime.h>
#include <hip/hip_bf16.h>

using bf16 = __hip_bfloat16;
typedef __attribute__((ext_vector_type(8))) short s16x8;
typedef __attribute__((ext_vector_type(4))) float f32x4;
typedef unsigned int u32;

__device__ __forceinline__ float b2f(short u) {
    union { float f; u32 i; } x; x.i = ((u32)(unsigned short)u) << 16; return x.f;
}
__device__ __forceinline__ short f2b(float f) {
    bf16 h = (bf16)f; return *(short*)&h;
}

// ---- convert weights fp32 -> bf16 (10 tensors; q/k/v read pristine in proj).
// Lesson (R5/R8/R11): pre-converted bf16 for the REUSED operand (weights);
// fp32 convert-on-stage only for the streamed-once A side from pristine d_in. ----
struct CvtArgs { const float* src[10]; bf16* dst[10]; int n[10]; int bb[11]; };
__global__ __launch_bounds__(256)
void convert_kernel(CvtArgs a) {
    const int blk = blockIdx.x;
    int s = 0;
    while (s < 9 && blk >= a.bb[s + 1]) ++s;
    const int base = (blk - a.bb[s]) * 1024 + threadIdx.x * 4;
    if (base >= a.n[s]) return;            // all n % 4 == 0
    float4 v = *(const float4*)(a.src[s] + base);
    ushort4 o;
    o.x = (unsigned short)f2b(v.x); o.y = (unsigned short)f2b(v.y);
    o.z = (unsigned short)f2b(v.z); o.w = (unsigned short)f2b(v.w);
    *(ushort4*)(a.dst[s] + base) = o;
}

// ---- register-pipelined GEMM core (R6/R9): C = A @ W^T + bias ----
template<int BM, int BN, bool A_F32, bool OUT_F32>
__device__ __forceinline__ void gemm_pipe(
    const void* __restrict__ A, const bf16* __restrict__ W,
    const bf16* __restrict__ bias, void* __restrict__ out,
    int m0, int n0, int N, int K, bf16* lA, bf16* lB) {
    constexpr int WM = BM / 2, WN = BN / 2, FM = WM / 16, FN = WN / 16;
    constexpr int SA = BM / 64, SB = BN / 64;   // 16B reg slots per thread
    const int tid = threadIdx.x;
    const int wave = tid >> 6, lane = tid & 63;
    const int wr = wave >> 1, wc = wave & 1;
    const int quad = lane >> 4, lm = lane & 15;
    uint4 ra[SA], rb[SB];

    auto loadA = [&](int k0) {
#pragma unroll
        for (int q = 0; q < SA; ++q) {
            const int sl = q * 256 + tid, row = sl >> 2, col = (sl & 3) * 8;
            if (A_F32) {
                const float* g = (const float*)A + (size_t)(m0 + row) * K + k0 + col;
                float4 f0 = *(const float4*)g;
                float4 f1 = *(const float4*)(g + 4);
                union { uint4 u; short h[8]; } p;
                p.h[0] = f2b(f0.x); p.h[1] = f2b(f0.y); p.h[2] = f2b(f0.z); p.h[3] = f2b(f0.w);
                p.h[4] = f2b(f1.x); p.h[5] = f2b(f1.y); p.h[6] = f2b(f1.z); p.h[7] = f2b(f1.w);
                ra[q] = p.u;
            } else {
                ra[q] = *(const uint4*)((const bf16*)A + (size_t)(m0 + row) * K + k0 + col);
            }
        }
    };
    auto loadB = [&](int k0) {
#pragma unroll
        for (int q = 0; q < SB; ++q) {
            const int sl = q * 256 + tid, row = sl >> 2, col = (sl & 3) * 8;
            rb[q] = *(const uint4*)(W + (size_t)(n0 + row) * K + k0 + col);
        }
    };

    f32x4 acc[FM][FN] = {};
    loadA(0); loadB(0);
    for (int k0 = 0; k0 < K; k0 += 32) {
#pragma unroll
        for (int q = 0; q < SA; ++q) *(uint4*)(lA + (q * 256 + tid) * 8) = ra[q];
#pragma unroll
        for (int q = 0; q < SB; ++q) *(uint4*)(lB + (q * 256 + tid) * 8) = rb[q];
        __syncthreads();
        if (k0 + 32 < K) { loadA(k0 + 32); loadB(k0 + 32); }   // overlaps MFMA below
        s16x8 af[FM], bf_[FN];
#pragma unroll
        for (int i = 0; i < FM; ++i)
            af[i] = *(const s16x8*)&lA[(wr * WM + i * 16 + lm) * 32 + quad * 8];
#pragma unroll
        for (int j = 0; j < FN; ++j)
            bf_[j] = *(const s16x8*)&lB[(wc * WN + j * 16 + lm) * 32 + quad * 8];
#pragma unroll
        for (int i = 0; i < FM; ++i)
#pragma unroll
            for (int j = 0; j < FN; ++j)
                acc[i][j] = __builtin_amdgcn_mfma_f32_16x16x32_bf16(af[i], bf_[j], acc[i][j], 0, 0, 0);
        __syncthreads();
    }
#pragma unroll
    for (int i = 0; i < FM; ++i) {
        const int rbase = m0 + wr * WM + i * 16 + quad * 4;
#pragma unroll
        for (int j = 0; j < FN; ++j) {
            const int col = n0 + wc * WN + j * 16 + lm;
            const float bv = (float)bias[col];
#pragma unroll
            for (int r = 0; r < 4; ++r) {
                float v = acc[i][j][r] + bv;
                size_t off = (size_t)(rbase + r) * N + col;
                if (OUT_F32) ((float*)out)[off] = v;
                else         ((bf16*)out)[off] = (bf16)v;
            }
        }
    }
}

// ---- fused Q/K/V projection: 768 blocks (3/CU), 128x64 tiles, XCD-swizzled ----
__global__ __launch_bounds__(256)
void proj_kernel(const float* __restrict__ q, const float* __restrict__ k,
                 const float* __restrict__ v,
                 const bf16* __restrict__ Qkc, const bf16* __restrict__ Kkc,
                 const bf16* __restrict__ Vkc,
                 const bf16* __restrict__ Qbc, const bf16* __restrict__ Kbc,
                 const bf16* __restrict__ Vbc,
                 float* __restrict__ qp, float* __restrict__ kp,
                 bf16* __restrict__ vp) {
    __shared__ __align__(16) bf16 lA[128 * 32];
    __shared__ __align__(16) bf16 lB[64 * 32];
    const int L = blockIdx.x, xcd = L & 7, i = L >> 3;
    const int m0 = (xcd * 2 + i / 48) * 128;
    const int nid = i % 48;
    if (nid < 10)
        gemm_pipe<128, 64, true, true >(q, Qkc, Qbc, qp, m0, nid * 64, 640, 640, lA, lB);
    else if (nid < 20)
        gemm_pipe<128, 64, true, true >(k, Kkc, Kbc, kp, m0, (nid - 10) * 64, 640, 640, lA, lB);
    else
        gemm_pipe<128, 64, true, false>(v, Vkc, Vbc, vp, m0, (nid - 20) * 64, 1792, 640, lA, lB);
}

// ---- collapse GEMM: 320 blocks of 64x64, K=1792, XCD-swizzled ----
__global__ __launch_bounds__(256)
void collapse_kernel(const bf16* __restrict__ atn, const bf16* __restrict__ Ckc,
                     const bf16* __restrict__ Cbc, float* __restrict__ out) {
    __shared__ __align__(16) bf16 lA[64 * 32];
    __shared__ __align__(16) bf16 lB[64 * 32];
    const int L = blockIdx.x, xcd = L & 7, i = L >> 3;
    const int m0 = (xcd * 4 + i / 10) * 64;
    const int n0 = (i % 10) * 64;
    gemm_pipe<64, 64, false, true>(atn, Ckc, Cbc, out, m0, n0, 640, 1792, lA, lB);
}

// ---- attention core: one block per position, XCD-swizzled ----
__global__ __launch_bounds__(256)
void attn_v4(const float* __restrict__ qp, const float* __restrict__ kp,
             const bf16* __restrict__ vp,
             const bf16* __restrict__ Kbc, const bf16* __restrict__ Vbc,
             const bf16* __restrict__ Skc, const bf16* __restrict__ Sbc,
             bf16* __restrict__ atn) {
    const int pos = ((blockIdx.x & 7) << 8) | (blockIdx.x >> 3);  // XCD-contiguous
    const int b = pos >> 10, l = pos & 1023;
    const int t = threadIdx.x;
    __shared__ float qs[640];
    __shared__ float sc5[5 * 32];
    __shared__ float sc14[14 * 32];
    __shared__ float w14T[32 * 14];   // transposed: [tap][head]

    if (t < 160) ((float4*)qs)[t] = ((const float4*)(qp + (size_t)pos * 640))[t];
    __syncthreads();

    // Phase A: score[s][j] = q[s].kwin[s][j]; 8 lanes/dot, stride-32 interleave
    {
        const int j = t >> 3, p = t & 7;
#pragma unroll
        for (int s = 0; s < 5; ++s) {
            const int dil = (s < 2) ? 1 : (1 << (s - 1));
            const int pl = (31 * dil) >> 1;
            const int row = l + j * dil - pl;
            const float* q = qs + s * 128 + p * 4;
            float acc = 0.f;
            if (row >= 0 && row < 1024) {
                const float* kr = kp + (size_t)((b << 10) | row) * 640 + s * 128 + p * 4;
#pragma unroll
                for (int g = 0; g < 4; ++g) {
                    float4 kv = *(const float4*)(kr + g * 32);
                    float4 qv = *(const float4*)(q + g * 32);
                    acc += qv.x * kv.x + qv.y * kv.y + qv.z * kv.z + qv.w * kv.w;
                }
            } else {
                const bf16* kb = Kbc + s * 128 + p * 4;   // pad rows project the bias
#pragma unroll
                for (int g = 0; g < 4; ++g) {
                    float4 qv = *(const float4*)(q + g * 32);
                    acc += qv.x * (float)kb[g * 32] + qv.y * (float)kb[g * 32 + 1]
                         + qv.z * (float)kb[g * 32 + 2] + qv.w * (float)kb[g * 32 + 3];
                }
            }
            acc += __shfl_xor(acc, 1);
            acc += __shfl_xor(acc, 2);
            acc += __shfl_xor(acc, 4);
            if (p == 0) sc5[s * 32 + j] = acc;
        }
    }
    __syncthreads();

    // Phase B: supersample + positional resampling (448 outputs), vectorized Sk
    for (int idx = t; idx < 448; idx += 256) {
        const int h = idx >> 5;
        const int s = (h < 5) ? 0 : (h < 10) ? 1 : (h < 12) ? 2 : (h == 12) ? 3 : 4;
        const s16x8* sk = (const s16x8*)((const short*)Skc + idx * 32);
        const float* sc = sc5 + s * 32;
        float acc = b2f(((const short*)Sbc)[idx]);
#pragma unroll
        for (int g = 0; g < 4; ++g) {
            s16x8 kk = sk[g];
#pragma unroll
            for (int r = 0; r < 8; ++r) acc += sc[g * 8 + r] * b2f(kk[r]);
        }
        sc14[idx] = acc;
    }
    __syncthreads();

    // Phase C: softmax, 16 lanes/head (2 taps each), shuffle-reduce width 16
    if (t < 224) {
        const int h = t >> 4, u = t & 15;
        float s0 = sc14[h * 32 + u], s1 = sc14[h * 32 + u + 16];
        float mx = fmaxf(s0, s1);
#pragma unroll
        for (int m = 1; m < 16; m <<= 1) mx = fmaxf(mx, __shfl_xor(mx, m));
        float e0 = __expf(s0 - mx), e1 = __expf(s1 - mx);
        float sum = e0 + e1;
#pragma unroll
        for (int m = 1; m < 16; m <<= 1) sum += __shfl_xor(sum, m);
        float inv = 1.f / sum;
        w14T[u * 14 + h] = e0 * inv;
        w14T[(u + 16) * 14 + h] = e1 * inv;
    }
    __syncthreads();

    // Phase D: attn[h][d8] = sum_j w[j][h] * vwin[h][j][d8]
    if (t < 224) {
        const int h = t >> 4, d8 = (t & 15) * 8;
        const int dil = (h < 10) ? 1 : (h < 12) ? 2 : (h == 12) ? 4 : 8;
        const int pl = (31 * dil) >> 1;
        const int col = h * 128 + d8;
        float acc[8] = {};
#pragma unroll
        for (int j = 0; j < 32; ++j) {
            const int row = l + j * dil - pl;
            const short* src = (row >= 0 && row < 1024)
                ? (const short*)vp + (size_t)((b << 10) | row) * 1792 + col
                : (const short*)Vbc + col;     // pad rows project the bias
            s16x8 v8 = *(const s16x8*)src;
            const float w = w14T[j * 14 + h];
#pragma unroll
            for (int r = 0; r < 8; ++r) acc[r] += w * b2f(v8[r]);
        }
        union { uint4 u; short h16[8]; } o;
#pragma unroll
        for (int r = 0; r < 8; ++r) o.h16[r] = f2b(acc[r]);
        *(uint4*)((short*)atn + (size_t)pos * 1792 + col) = o.u;
    }
}

extern "C" void kernel_launch(void* const* d_in, const int* in_sizes, int n_in,
                              void* d_out, int out_size, void* d_ws, size_t ws_size,
                              hipStream_t stream) {
    const int M = 2048;
    char* w = (char*)d_ws;
    size_t off = 0;
    auto alloc = [&](size_t bytes) -> char* {
        off = (off + 255) & ~(size_t)255;
        char* p = w + off; off += bytes; return p;
    };
    bf16* Qkc = (bf16*)alloc(409600 * 2);
    bf16* Qbc = (bf16*)alloc(640 * 2);
    bf16* Kkc = (bf16*)alloc(409600 * 2);
    bf16* Kbc = (bf16*)alloc(640 * 2);
    bf16* Vkc = (bf16*)alloc(1146880 * 2);
    bf16* Vbc = (bf16*)alloc(1792 * 2);
    bf16* Skc = (bf16*)alloc(14336 * 2);
    bf16* Sbc = (bf16*)alloc(448 * 2);
    bf16* Ckc = (bf16*)alloc(1146880 * 2);
    bf16* Cbc = (bf16*)alloc(640 * 2);
    float* qp = (float*)alloc((size_t)M * 640 * 4);
    float* kp = (float*)alloc((size_t)M * 640 * 4);
    bf16*  vp = (bf16*)alloc((size_t)M * 1792 * 2);
    bf16*  atn = (bf16*)alloc((size_t)M * 1792 * 2);

    CvtArgs ca;
    bf16* dsts[10] = {Qkc, Qbc, Kkc, Kbc, Vkc, Vbc, Skc, Sbc, Ckc, Cbc};
    const int ns[10] = {409600, 640, 409600, 640, 1146880, 1792, 14336, 448, 1146880, 640};
    int cum = 0;
    for (int i = 0; i < 10; ++i) {
        ca.src[i] = (const float*)d_in[3 + i];
        ca.dst[i] = dsts[i];
        ca.n[i] = ns[i];
        ca.bb[i] = cum;
        cum += (ns[i] + 1023) / 1024;
    }
    ca.bb[10] = cum;

    dim3 blk(256);
    convert_kernel<<<dim3(cum), blk, 0, stream>>>(ca);
    proj_kernel<<<dim3(768), blk, 0, stream>>>(
        (const float*)d_in[0], (const float*)d_in[1], (const float*)d_in[2],
        Qkc, Kkc, Vkc, Qbc, Kbc, Vbc, qp, kp, vp);
    attn_v4<<<dim3(2048), blk, 0, stream>>>(qp, kp, vp, Kbc, Vbc, Skc, Sbc, atn);
    collapse_kernel<<<dim3(320), blk, 0, stream>>>(atn, Ckc, Cbc, (float*)d_out);
}

// Round 13
// 162.267 us; speedup vs baseline: 1.2201x; 1.0205x over previous
//
#include <hip/hip_runtime.h>
#include <hip/hip_bf16.h>

using bf16 = __hip_bfloat16;
typedef __attribute__((ext_vector_type(8))) short s16x8;
typedef __attribute__((ext_vector_type(4))) short s16x4;
typedef __attribute__((ext_vector_type(4))) float f32x4;
typedef unsigned int u32;

__device__ __forceinline__ float b2f(short u) {
    union { float f; u32 i; } x; x.i = ((u32)(unsigned short)u) << 16; return x.f;
}
__device__ __forceinline__ short f2b(float f) {
    bf16 h = (bf16)f; return *(short*)&h;
}

// ---- convert weights fp32 -> bf16 (10 tensors; q/k/v read pristine in proj).
// Lesson (R5/R8/R11): pre-converted bf16 for the REUSED operand (weights);
// fp32 convert-on-stage only for the streamed-once A side from pristine d_in. ----
struct CvtArgs { const float* src[10]; bf16* dst[10]; int n[10]; int bb[11]; };
__global__ __launch_bounds__(256)
void convert_kernel(CvtArgs a) {
    const int blk = blockIdx.x;
    int s = 0;
    while (s < 9 && blk >= a.bb[s + 1]) ++s;
    const int base = (blk - a.bb[s]) * 1024 + threadIdx.x * 4;
    if (base >= a.n[s]) return;            // all n % 4 == 0
    float4 v = *(const float4*)(a.src[s] + base);
    ushort4 o;
    o.x = (unsigned short)f2b(v.x); o.y = (unsigned short)f2b(v.y);
    o.z = (unsigned short)f2b(v.z); o.w = (unsigned short)f2b(v.w);
    *(ushort4*)(a.dst[s] + base) = o;
}

// ---- register-pipelined GEMM core (R6/R9): C = A @ W^T + bias ----
template<int BM, int BN, bool A_F32, bool OUT_F32>
__device__ __forceinline__ void gemm_pipe(
    const void* __restrict__ A, const bf16* __restrict__ W,
    const bf16* __restrict__ bias, void* __restrict__ out,
    int m0, int n0, int N, int K, bf16* lA, bf16* lB) {
    constexpr int WM = BM / 2, WN = BN / 2, FM = WM / 16, FN = WN / 16;
    constexpr int SA = BM / 64, SB = BN / 64;   // 16B reg slots per thread
    const int tid = threadIdx.x;
    const int wave = tid >> 6, lane = tid & 63;
    const int wr = wave >> 1, wc = wave & 1;
    const int quad = lane >> 4, lm = lane & 15;
    uint4 ra[SA], rb[SB];

    auto loadA = [&](int k0) {
#pragma unroll
        for (int q = 0; q < SA; ++q) {
            const int sl = q * 256 + tid, row = sl >> 2, col = (sl & 3) * 8;
            if (A_F32) {
                const float* g = (const float*)A + (size_t)(m0 + row) * K + k0 + col;
                float4 f0 = *(const float4*)g;
                float4 f1 = *(const float4*)(g + 4);
                union { uint4 u; short h[8]; } p;
                p.h[0] = f2b(f0.x); p.h[1] = f2b(f0.y); p.h[2] = f2b(f0.z); p.h[3] = f2b(f0.w);
                p.h[4] = f2b(f1.x); p.h[5] = f2b(f1.y); p.h[6] = f2b(f1.z); p.h[7] = f2b(f1.w);
                ra[q] = p.u;
            } else {
                ra[q] = *(const uint4*)((const bf16*)A + (size_t)(m0 + row) * K + k0 + col);
            }
        }
    };
    auto loadB = [&](int k0) {
#pragma unroll
        for (int q = 0; q < SB; ++q) {
            const int sl = q * 256 + tid, row = sl >> 2, col = (sl & 3) * 8;
            rb[q] = *(const uint4*)(W + (size_t)(n0 + row) * K + k0 + col);
        }
    };

    f32x4 acc[FM][FN] = {};
    loadA(0); loadB(0);
    for (int k0 = 0; k0 < K; k0 += 32) {
#pragma unroll
        for (int q = 0; q < SA; ++q) *(uint4*)(lA + (q * 256 + tid) * 8) = ra[q];
#pragma unroll
        for (int q = 0; q < SB; ++q) *(uint4*)(lB + (q * 256 + tid) * 8) = rb[q];
        __syncthreads();
        if (k0 + 32 < K) { loadA(k0 + 32); loadB(k0 + 32); }   // overlaps MFMA below
        s16x8 af[FM], bf_[FN];
#pragma unroll
        for (int i = 0; i < FM; ++i)
            af[i] = *(const s16x8*)&lA[(wr * WM + i * 16 + lm) * 32 + quad * 8];
#pragma unroll
        for (int j = 0; j < FN; ++j)
            bf_[j] = *(const s16x8*)&lB[(wc * WN + j * 16 + lm) * 32 + quad * 8];
#pragma unroll
        for (int i = 0; i < FM; ++i)
#pragma unroll
            for (int j = 0; j < FN; ++j)
                acc[i][j] = __builtin_amdgcn_mfma_f32_16x16x32_bf16(af[i], bf_[j], acc[i][j], 0, 0, 0);
        __syncthreads();
    }
#pragma unroll
    for (int i = 0; i < FM; ++i) {
        const int rbase = m0 + wr * WM + i * 16 + quad * 4;
#pragma unroll
        for (int j = 0; j < FN; ++j) {
            const int col = n0 + wc * WN + j * 16 + lm;
            const float bv = (float)bias[col];
#pragma unroll
            for (int r = 0; r < 4; ++r) {
                float v = acc[i][j][r] + bv;
                size_t off = (size_t)(rbase + r) * N + col;
                if (OUT_F32) ((float*)out)[off] = v;
                else         ((bf16*)out)[off] = (bf16)v;
            }
        }
    }
}

// ---- fused Q/K/V projection: 768 blocks (3/CU), 128x64 tiles, XCD-swizzled.
// qp/kp/vp now ALL bf16 (R13: halves attn Phase A traffic + Q/K write bytes). ----
__global__ __launch_bounds__(256)
void proj_kernel(const float* __restrict__ q, const float* __restrict__ k,
                 const float* __restrict__ v,
                 const bf16* __restrict__ Qkc, const bf16* __restrict__ Kkc,
                 const bf16* __restrict__ Vkc,
                 const bf16* __restrict__ Qbc, const bf16* __restrict__ Kbc,
                 const bf16* __restrict__ Vbc,
                 bf16* __restrict__ qp, bf16* __restrict__ kp,
                 bf16* __restrict__ vp) {
    __shared__ __align__(16) bf16 lA[128 * 32];
    __shared__ __align__(16) bf16 lB[64 * 32];
    const int L = blockIdx.x, xcd = L & 7, i = L >> 3;
    const int m0 = (xcd * 2 + i / 48) * 128;
    const int nid = i % 48;
    if (nid < 10)
        gemm_pipe<128, 64, true, false>(q, Qkc, Qbc, qp, m0, nid * 64, 640, 640, lA, lB);
    else if (nid < 20)
        gemm_pipe<128, 64, true, false>(k, Kkc, Kbc, kp, m0, (nid - 10) * 64, 640, 640, lA, lB);
    else
        gemm_pipe<128, 64, true, false>(v, Vkc, Vbc, vp, m0, (nid - 20) * 64, 1792, 640, lA, lB);
}

// ---- collapse GEMM: 320 blocks of 64x64, K=1792, XCD-swizzled ----
__global__ __launch_bounds__(256)
void collapse_kernel(const bf16* __restrict__ atn, const bf16* __restrict__ Ckc,
                     const bf16* __restrict__ Cbc, float* __restrict__ out) {
    __shared__ __align__(16) bf16 lA[64 * 32];
    __shared__ __align__(16) bf16 lB[64 * 32];
    const int L = blockIdx.x, xcd = L & 7, i = L >> 3;
    const int m0 = (xcd * 4 + i / 10) * 64;
    const int n0 = (i % 10) * 64;
    gemm_pipe<64, 64, false, true>(atn, Ckc, Cbc, out, m0, n0, 640, 1792, lA, lB);
}

// ---- attention core: one block per position, XCD-swizzled. kp/qp bf16. ----
__global__ __launch_bounds__(256)
void attn_v6(const bf16* __restrict__ qp, const bf16* __restrict__ kp,
             const bf16* __restrict__ vp,
             const bf16* __restrict__ Kbc, const bf16* __restrict__ Vbc,
             const bf16* __restrict__ Skc, const bf16* __restrict__ Sbc,
             bf16* __restrict__ atn) {
    const int pos = ((blockIdx.x & 7) << 8) | (blockIdx.x >> 3);  // XCD-contiguous
    const int b = pos >> 10, l = pos & 1023;
    const int t = threadIdx.x;
    __shared__ float qs[640];          // q kept fp32 in LDS (conflict-free reads)
    __shared__ float sc5[5 * 32];
    __shared__ float sc14[14 * 32];
    __shared__ float w14T[32 * 14];    // transposed: [tap][head]

    if (t < 80) {
        s16x8 qv = *(const s16x8*)((const short*)qp + (size_t)pos * 640 + t * 8);
#pragma unroll
        for (int r = 0; r < 8; ++r) qs[t * 8 + r] = b2f(qv[r]);
    }
    __syncthreads();

    // Phase A: score[s][j] = q[s].kwin[s][j]; 8 lanes/dot, stride-32 interleave
    // kp rows are bf16 -> 8B loads per 4-elem chunk (half the bytes of fp32).
    {
        const int j = t >> 3, p = t & 7;
#pragma unroll
        for (int s = 0; s < 5; ++s) {
            const int dil = (s < 2) ? 1 : (1 << (s - 1));
            const int pl = (31 * dil) >> 1;
            const int row = l + j * dil - pl;
            const float* q = qs + s * 128 + p * 4;
            const short* kr = (row >= 0 && row < 1024)
                ? (const short*)kp + (size_t)((b << 10) | row) * 640 + s * 128 + p * 4
                : (const short*)Kbc + s * 128 + p * 4;   // pad rows project the bias
            float acc = 0.f;
#pragma unroll
            for (int g = 0; g < 4; ++g) {
                s16x4 kv = *(const s16x4*)(kr + g * 32);
                float4 qv = *(const float4*)(q + g * 32);
                acc += qv.x * b2f(kv[0]) + qv.y * b2f(kv[1])
                     + qv.z * b2f(kv[2]) + qv.w * b2f(kv[3]);
            }
            acc += __shfl_xor(acc, 1);
            acc += __shfl_xor(acc, 2);
            acc += __shfl_xor(acc, 4);
            if (p == 0) sc5[s * 32 + j] = acc;
        }
    }
    __syncthreads();

    // Phase B: supersample + positional resampling (448 outputs), vectorized Sk
    for (int idx = t; idx < 448; idx += 256) {
        const int h = idx >> 5;
        const int s = (h < 5) ? 0 : (h < 10) ? 1 : (h < 12) ? 2 : (h == 12) ? 3 : 4;
        const s16x8* sk = (const s16x8*)((const short*)Skc + idx * 32);
        const float* sc = sc5 + s * 32;
        float acc = b2f(((const short*)Sbc)[idx]);
#pragma unroll
        for (int g = 0; g < 4; ++g) {
            s16x8 kk = sk[g];
#pragma unroll
            for (int r = 0; r < 8; ++r) acc += sc[g * 8 + r] * b2f(kk[r]);
        }
        sc14[idx] = acc;
    }
    __syncthreads();

    // Phase C: softmax, 16 lanes/head (2 taps each), shuffle-reduce width 16
    if (t < 224) {
        const int h = t >> 4, u = t & 15;
        float s0 = sc14[h * 32 + u], s1 = sc14[h * 32 + u + 16];
        float mx = fmaxf(s0, s1);
#pragma unroll
        for (int m = 1; m < 16; m <<= 1) mx = fmaxf(mx, __shfl_xor(mx, m));
        float e0 = __expf(s0 - mx), e1 = __expf(s1 - mx);
        float sum = e0 + e1;
#pragma unroll
        for (int m = 1; m < 16; m <<= 1) sum += __shfl_xor(sum, m);
        float inv = 1.f / sum;
        w14T[u * 14 + h] = e0 * inv;
        w14T[(u + 16) * 14 + h] = e1 * inv;
    }
    __syncthreads();

    // Phase D: attn[h][d8] = sum_j w[j][h] * vwin[h][j][d8]
    if (t < 224) {
        const int h = t >> 4, d8 = (t & 15) * 8;
        const int dil = (h < 10) ? 1 : (h < 12) ? 2 : (h == 12) ? 4 : 8;
        const int pl = (31 * dil) >> 1;
        const int col = h * 128 + d8;
        float acc[8] = {};
#pragma unroll
        for (int j = 0; j < 32; ++j) {
            const int row = l + j * dil - pl;
            const short* src = (row >= 0 && row < 1024)
                ? (const short*)vp + (size_t)((b << 10) | row) * 1792 + col
                : (const short*)Vbc + col;     // pad rows project the bias
            s16x8 v8 = *(const s16x8*)src;
            const float w = w14T[j * 14 + h];
#pragma unroll
            for (int r = 0; r < 8; ++r) acc[r] += w * b2f(v8[r]);
        }
        union { uint4 u; short h16[8]; } o;
#pragma unroll
        for (int r = 0; r < 8; ++r) o.h16[r] = f2b(acc[r]);
        *(uint4*)((short*)atn + (size_t)pos * 1792 + col) = o.u;
    }
}

extern "C" void kernel_launch(void* const* d_in, const int* in_sizes, int n_in,
                              void* d_out, int out_size, void* d_ws, size_t ws_size,
                              hipStream_t stream) {
    const int M = 2048;
    char* w = (char*)d_ws;
    size_t off = 0;
    auto alloc = [&](size_t bytes) -> char* {
        off = (off + 255) & ~(size_t)255;
        char* p = w + off; off += bytes; return p;
    };
    bf16* Qkc = (bf16*)alloc(409600 * 2);
    bf16* Qbc = (bf16*)alloc(640 * 2);
    bf16* Kkc = (bf16*)alloc(409600 * 2);
    bf16* Kbc = (bf16*)alloc(640 * 2);
    bf16* Vkc = (bf16*)alloc(1146880 * 2);
    bf16* Vbc = (bf16*)alloc(1792 * 2);
    bf16* Skc = (bf16*)alloc(14336 * 2);
    bf16* Sbc = (bf16*)alloc(448 * 2);
    bf16* Ckc = (bf16*)alloc(1146880 * 2);
    bf16* Cbc = (bf16*)alloc(640 * 2);
    bf16* qp = (bf16*)alloc((size_t)M * 640 * 2);
    bf16* kp = (bf16*)alloc((size_t)M * 640 * 2);
    bf16* vp = (bf16*)alloc((size_t)M * 1792 * 2);
    bf16* atn = (bf16*)alloc((size_t)M * 1792 * 2);

    CvtArgs ca;
    bf16* dsts[10] = {Qkc, Qbc, Kkc, Kbc, Vkc, Vbc, Skc, Sbc, Ckc, Cbc};
    const int ns[10] = {409600, 640, 409600, 640, 1146880, 1792, 14336, 448, 1146880, 640};
    int cum = 0;
    for (int i = 0; i < 10; ++i) {
        ca.src[i] = (const float*)d_in[3 + i];
        ca.dst[i] = dsts[i];
        ca.n[i] = ns[i];
        ca.bb[i] = cum;
        cum += (ns[i] + 1023) / 1024;
    }
    ca.bb[10] = cum;

    dim3 blk(256);
    convert_kernel<<<dim3(cum), blk, 0, stream>>>(ca);
    proj_kernel<<<dim3(768), blk, 0, stream>>>(
        (const float*)d_in[0], (const float*)d_in[1], (const float*)d_in[2],
        Qkc, Kkc, Vkc, Qbc, Kbc, Vbc, qp, kp, vp);
    attn_v6<<<dim3(2048), blk, 0, stream>>>(qp, kp, vp, Kbc, Vbc, Skc, Sbc, atn);
    collapse_kernel<<<dim3(320), blk, 0, stream>>>(atn, Ckc, Cbc, (float*)d_out);
}